// Round 4
// baseline (312.220 us; speedup 1.0000x reference)
//
#include <hip/hip_runtime.h>
#include <hip/hip_bf16.h>
#include <cstdint>
#include <cstddef>

// Problem constants
constexpr int Bb = 4;
constexpr int Tt = 2048;
constexpr int Mm = 1024;
constexpr int Hh = 2048;
constexpr int Ee = 8;
constexpr int Ss = Bb * Tt;   // 8192
constexpr int Cc = 2048;      // capacity per expert

typedef __attribute__((ext_vector_type(4))) float f32x4;
typedef __attribute__((ext_vector_type(8))) short bf16x8;

__device__ inline void load_lds16(const void* g, void* l) {
    __builtin_amdgcn_global_load_lds(
        (const __attribute__((address_space(1))) unsigned int*)g,
        (__attribute__((address_space(3))) unsigned int*)l, 16, 0, 0);
}

// ---------------- fused prep: w1 transpose+cast | w2sum/b2sum | gate + x->bf16 ----------------
// blocks [0,4096): w1 (E,M,H) fp32 -> w1t (E,H,M) bf16
// blocks [4096,8192): w2sum[e,h] = sum_m w2[e,h,m]   block 8192: b2sum
// blocks [8193,10241): gating (one wave per token) + xbf emit
__global__ __launch_bounds__(256) void k_prep(
    const float* __restrict__ w1, const float* __restrict__ w2, const float* __restrict__ b2,
    const float* __restrict__ x, const float* __restrict__ wg,
    __hip_bfloat16* __restrict__ w1t, float* __restrict__ w2sum, float* __restrict__ b2sum,
    int* __restrict__ esel, float* __restrict__ gates, __hip_bfloat16* __restrict__ xbf) {
    int bid = blockIdx.x;
    int t = threadIdx.x;
    if (bid < 4096) {
        // ---- w1 transpose: 64x64 tile; h-idx = bid&31, m-idx = (bid>>5)&15, e = bid>>9
        __shared__ float tile[64][65];
        int e = bid >> 9, m0 = ((bid >> 5) & 15) * 64, h0 = (bid & 31) * 64;
        const float* src = w1 + (size_t)e * Mm * Hh;
        #pragma unroll
        for (int i = 0; i < 4; i++) {
            int idx = t + i * 256;            // [0,1024)
            int r = idx >> 4, c4 = idx & 15;  // r: m-row, c4: h-chunk of 4
            float4 v = *(const float4*)(src + (size_t)(m0 + r) * Hh + h0 + c4 * 4);
            tile[r][c4 * 4 + 0] = v.x; tile[r][c4 * 4 + 1] = v.y;
            tile[r][c4 * 4 + 2] = v.z; tile[r][c4 * 4 + 3] = v.w;
        }
        __syncthreads();
        __hip_bfloat16* dst = w1t + (size_t)e * Hh * Mm;
        #pragma unroll
        for (int i = 0; i < 2; i++) {
            int idx = t + i * 256;            // [0,512)
            int r = idx >> 3, c8 = idx & 7;   // r: h-row, c8: m-chunk of 8
            __hip_bfloat16 tmp[8];
            #pragma unroll
            for (int k = 0; k < 8; k++) tmp[k] = __float2bfloat16(tile[c8 * 8 + k][r]);
            uint4 vv; __builtin_memcpy(&vv, tmp, 16);
            *(uint4*)(dst + (size_t)(h0 + r) * Mm + m0 + c8 * 8) = vv;
        }
    } else if (bid < 8192) {
        // ---- w2sum: 4 rows per block (one per wave)
        int wave = t >> 6, lane = t & 63;
        int r = (bid - 4096) * 4 + wave;   // r in [0, E*H)
        const float4* p = (const float4*)(w2 + (size_t)r * Mm);
        float s = 0.f;
        #pragma unroll
        for (int i = 0; i < 4; i++) { float4 v = p[lane + i * 64]; s += v.x + v.y + v.z + v.w; }
        #pragma unroll
        for (int off = 32; off; off >>= 1) s += __shfl_down(s, off);
        if (lane == 0) w2sum[r] = s;
    } else if (bid == 8192) {
        // ---- b2sum: 4 waves x 2 half-waves = 8 experts
        int wave = t >> 6, lane = t & 63;
        int e = wave * 2 + (lane >> 5);
        int l = lane & 31;
        const float4* p = (const float4*)(b2 + (size_t)e * Mm);
        float s = 0.f;
        #pragma unroll
        for (int i = 0; i < 8; i++) { float4 v = p[l + i * 32]; s += v.x + v.y + v.z + v.w; }
        #pragma unroll
        for (int off = 16; off; off >>= 1) s += __shfl_down(s, off);
        if (l == 0) b2sum[e] = s;
    } else {
        // ---- gating: one wave per token + bf16 emit
        int gb = bid - 8193;
        int s = (gb * 256 + t) >> 6;   // token id
        int lane = t & 63;
        const float4* xr = (const float4*)(x + (size_t)s * Mm);
        const float4* wgr = (const float4*)wg;
        float acc[8];
        #pragma unroll
        for (int e = 0; e < 8; e++) acc[e] = 0.f;
        #pragma unroll
        for (int i = 0; i < 4; i++) {
            float4 xv = xr[lane + i * 64];
            __hip_bfloat16 tb[4];
            tb[0] = __float2bfloat16(xv.x); tb[1] = __float2bfloat16(xv.y);
            tb[2] = __float2bfloat16(xv.z); tb[3] = __float2bfloat16(xv.w);
            uint2 u; __builtin_memcpy(&u, tb, 8);
            *(uint2*)(xbf + (size_t)s * Mm + (lane + i * 64) * 4) = u;
            int mbase = (lane + i * 64) * 4;
            #pragma unroll
            for (int k = 0; k < 4; k++) {
                int m = mbase + k;
                float xm = (k == 0) ? xv.x : (k == 1) ? xv.y : (k == 2) ? xv.z : xv.w;
                float4 w0 = wgr[m * 2], w1v = wgr[m * 2 + 1];
                acc[0] += xm * w0.x;  acc[1] += xm * w0.y;  acc[2] += xm * w0.z;  acc[3] += xm * w0.w;
                acc[4] += xm * w1v.x; acc[5] += xm * w1v.y; acc[6] += xm * w1v.z; acc[7] += xm * w1v.w;
            }
        }
        #pragma unroll
        for (int off = 32; off; off >>= 1)
            #pragma unroll
            for (int e = 0; e < 8; e++) acc[e] += __shfl_down(acc[e], off);
        if (lane == 0) {
            float mx = acc[0];
            #pragma unroll
            for (int e = 1; e < 8; e++) mx = fmaxf(mx, acc[e]);
            float p[8], se = 0.f;
            #pragma unroll
            for (int e = 0; e < 8; e++) { p[e] = expf(acc[e] - mx); se += p[e]; }
            float inv = 1.f / se;
            #pragma unroll
            for (int e = 0; e < 8; e++) p[e] *= inv;
            int i0 = 0; float v0 = p[0];
            #pragma unroll
            for (int e = 1; e < 8; e++) if (p[e] > v0) { v0 = p[e]; i0 = e; }
            int i1 = -1; float v1 = -1.f;
            #pragma unroll
            for (int e = 0; e < 8; e++) if (e != i0 && p[e] > v1) { v1 = p[e]; i1 = e; }
            float den = v0 + v1 + 1e-9f;
            esel[s] = i0; esel[Ss + s] = i1;
            gates[s] = v0 / den; gates[Ss + s] = v1 / den;
        }
    }
}

// ---------------- positions: parallel 2-phase scan (j-major = linear d) ----------------
__global__ __launch_bounds__(256) void k_posA(const int* __restrict__ esel,
                                              int* __restrict__ lrank, int* __restrict__ blockhist) {
    int b = blockIdx.x, t = threadIdx.x;
    int d = b * 256 + t;
    int e = esel[d];
    int wave = t >> 6, lane = t & 63;
    __shared__ int wh[4][8];
    unsigned long long mymask = 0;
    #pragma unroll
    for (int q = 0; q < 8; q++) {
        unsigned long long m = __ballot(e == q);
        if (q == e) mymask = m;
        if (lane == 0) wh[wave][q] = (int)__popcll(m);
    }
    __syncthreads();
    int prefix = (int)__popcll(mymask & ((1ull << lane) - 1ull));
    for (int w = 0; w < wave; w++) prefix += wh[w][e];
    lrank[d] = prefix;
    if (t < 8) blockhist[b * 8 + t] = wh[0][t] + wh[1][t] + wh[2][t] + wh[3][t];
}

// parallel exclusive scan over the 64 block-histograms: wave q handles expert q
__global__ __launch_bounds__(512) void k_posB(const int* __restrict__ blockhist,
                                              int* __restrict__ blockbase) {
    int t = threadIdx.x;
    int wave = t >> 6, lane = t & 63;   // wave = expert q, lane = block b
    int v = blockhist[lane * 8 + wave];
    int x = v;
    #pragma unroll
    for (int off = 1; off < 64; off <<= 1) {
        int y = __shfl_up(x, off);
        if (lane >= off) x += y;
    }
    blockbase[lane * 8 + wave] = x - v;   // exclusive prefix
}

// ---------------- finalize positions + build inverse index srcidx[e][c] = token ----------------
__global__ __launch_bounds__(256) void k_sidx(const int* __restrict__ esel,
                                              const int* __restrict__ lrank,
                                              const int* __restrict__ blockbase,
                                              int* __restrict__ pos, int* __restrict__ srcidx) {
    int d = blockIdx.x * 256 + threadIdx.x;
    int e = esel[d];
    int p = blockbase[(d >> 8) * 8 + e] + lrank[d];
    pos[d] = p;
    if (p < Cc) srcidx[e * Cc + p] = d & (Ss - 1);
}

// ---------------- fused expert GEMM (A gathered via srcidx) + relu + w2sum reduction ----------------
// Round-6: prefetch depth 2 (3-buffer rotation, vmcnt(8) steady-state) on top of the
// round-5 coalesced+conflict-free LDS permutation. Loads for tile tt are issued two
// iterations early -> ~2 compute phases (~800 cyc) of latency cover (HBM ~900 cyc).
//   Slot s (16 B) holds row (s>>2), k-chunk c(s) = ((s&3) - ((s>>3)&3)) & 3.
//   Fragment read (r16, quad): slot r16*4 + ((quad + (r16>>1)) & 3)  -> 0 conflicts.
__global__ __launch_bounds__(256) void k_gemm(
    const __hip_bfloat16* __restrict__ xbf, const int* __restrict__ srcidx,
    const __hip_bfloat16* __restrict__ w1t,
    const float* __restrict__ b1, const float* __restrict__ w2sum,
    float* __restrict__ rowsum) {
    __shared__ __align__(16) __hip_bfloat16 As[3][128 * 32];
    __shared__ __align__(16) __hip_bfloat16 Bs[3][128 * 32];
    int bid = blockIdx.x;
    // XCD-affine: linear wg id % 8 = XCD. Expert e -> XCD e; whole w1t[e] (4 MB) fits that L2.
    int e = bid & 7;
    int tile = bid >> 3;
    // 4x4 block swizzle inside the expert: 16 consecutive tiles share 4 c-tiles x 4 h-tiles
    int sq = tile >> 4, in16 = tile & 15;
    int hb = (sq & 3) * 4 + (in16 & 3);
    int cb = (sq >> 2) * 4 + (in16 >> 2);
    int c0 = cb * 128, h0 = hb * 128;
    int t = threadIdx.x;
    int wave = t >> 6, lane = t & 63;
    int wm = wave >> 1, wn = wave & 1;
    int r16 = lane & 15, quad = lane >> 4;
    // staging decode: thread t fills slot t (rows 0-63) and slot 256+t (rows 64-127)
    //   row = t>>2, k-chunk qd = ((t&3) - ((t>>3)&3)) & 3
    int r_s = t >> 2;
    int qd = ((t & 3) - ((t >> 3) & 3)) & 3;
    int s0 = srcidx[e * Cc + c0 + r_s];
    int s1 = srcidx[e * Cc + c0 + 64 + r_s];
    const __hip_bfloat16* a0 = xbf + (size_t)s0 * Mm + qd * 8;
    const __hip_bfloat16* a1 = xbf + (size_t)s1 * Mm + qd * 8;
    const __hip_bfloat16* Bp = w1t + (size_t)e * Hh * Mm;
    const __hip_bfloat16* b0 = Bp + (size_t)(h0 + r_s) * Mm + qd * 8;
    const __hip_bfloat16* b1p = Bp + (size_t)(h0 + 64 + r_s) * Mm + qd * 8;
    // fragment-read slot offset within each 64-slot row-group
    int frag = r16 * 4 + ((quad + (r16 >> 1)) & 3);
    __hip_bfloat16* Abase = &As[0][0];
    __hip_bfloat16* Bbase = &Bs[0][0];
    f32x4 acc[4][4];
    #pragma unroll
    for (int i = 0; i < 4; i++)
        #pragma unroll
        for (int j = 0; j < 4; j++) acc[i][j] = (f32x4){0.f, 0.f, 0.f, 0.f};

    // prologue: stage tiles 0 and 1 (8 loads in flight)
    load_lds16(a0,       Abase + t * 8);
    load_lds16(a1,       Abase + (256 + t) * 8);
    load_lds16(b0,       Bbase + t * 8);
    load_lds16(b1p,      Bbase + (256 + t) * 8);
    load_lds16(a0 + 32,  Abase + 4096 + t * 8);
    load_lds16(a1 + 32,  Abase + 4096 + (256 + t) * 8);
    load_lds16(b0 + 32,  Bbase + 4096 + t * 8);
    load_lds16(b1p + 32, Bbase + 4096 + (256 + t) * 8);

    int cur = 0;   // buffer holding tile tt
    int p2 = 2;    // buffer for tile tt+2
    for (int tt = 0; tt < 32; ++tt) {
        __builtin_amdgcn_sched_barrier(0);
        if (tt < 30) {
            // stage tile tt+2 into buf (tt+2)%3 (reusing tile tt-1's buffer; all waves
            // passed iteration tt-1's trailing barrier, so it is fully consumed).
            int k0 = (tt + 2) * 32;
            __hip_bfloat16* Ad = Abase + p2 * 4096;
            __hip_bfloat16* Bd = Bbase + p2 * 4096;
            load_lds16(a0 + k0,  Ad + t * 8);
            load_lds16(a1 + k0,  Ad + (256 + t) * 8);
            load_lds16(b0 + k0,  Bd + t * 8);
            load_lds16(b1p + k0, Bd + (256 + t) * 8);
            // 12 outstanding (tiles tt, tt+1, tt+2); wait for tile tt's 4 only.
            asm volatile("s_waitcnt vmcnt(8)" ::: "memory");
        } else if (tt == 30) {
            // 8 outstanding (tiles 30, 31); wait for tile 30's 4.
            asm volatile("s_waitcnt vmcnt(4)" ::: "memory");
        } else {
            asm volatile("s_waitcnt vmcnt(0)" ::: "memory");
        }
        __builtin_amdgcn_s_barrier();          // all waves confirmed tile tt landed
        __builtin_amdgcn_sched_barrier(0);     // pin ds_reads below the barrier
        const __hip_bfloat16* Ar = Abase + cur * 4096;
        const __hip_bfloat16* Br = Bbase + cur * 4096;
        bf16x8 af[4], bfr[4];
        #pragma unroll
        for (int mi = 0; mi < 4; mi++)
            af[mi] = *(const bf16x8*)(Ar + (((wm * 4 + mi) * 64 + frag) * 8));
        #pragma unroll
        for (int ni = 0; ni < 4; ni++)
            bfr[ni] = *(const bf16x8*)(Br + (((wn * 4 + ni) * 64 + frag) * 8));
        #pragma unroll
        for (int mi = 0; mi < 4; mi++)
            #pragma unroll
            for (int ni = 0; ni < 4; ni++)
                acc[mi][ni] = __builtin_amdgcn_mfma_f32_16x16x32_bf16(af[mi], bfr[ni], acc[mi][ni], 0, 0, 0);
        __builtin_amdgcn_sched_barrier(0);     // pin ds_reads above the trailing barrier
        __builtin_amdgcn_s_barrier();          // all waves done reading buf[cur] -> reusable
        cur = (cur == 2) ? 0 : cur + 1;
        p2  = (p2 == 2) ? 0 : p2 + 1;
    }

    // epilogue: relu(s + b1) * w2sum, reduce over h, atomic into rowsum[e, c]
    float b1v[4], wsv[4];
    #pragma unroll
    for (int ni = 0; ni < 4; ni++) {
        int hg = h0 + wn * 64 + ni * 16 + r16;
        b1v[ni] = b1[e * Hh + hg];
        wsv[ni] = w2sum[e * Hh + hg];
    }
    #pragma unroll
    for (int mi = 0; mi < 4; mi++) {
        #pragma unroll
        for (int r = 0; r < 4; r++) {
            float val = 0.f;
            #pragma unroll
            for (int ni = 0; ni < 4; ni++) {
                float sv = acc[mi][ni][r] + b1v[ni];
                val += fmaxf(sv, 0.f) * wsv[ni];
            }
            #pragma unroll
            for (int off = 1; off < 16; off <<= 1) val += __shfl_xor(val, off);
            if (r16 == 0) {
                int cg = c0 + wm * 64 + mi * 16 + quad * 4 + r;
                atomicAdd(&rowsum[e * Cc + cg], val);
            }
        }
    }
}

// ---------------- combine (parallel gather) ----------------
__global__ __launch_bounds__(256) void k_combine(
    const int* __restrict__ esel, const int* __restrict__ pos,
    const float* __restrict__ gates, const float* __restrict__ rowsum,
    const float* __restrict__ b2sum, float* __restrict__ vals) {
    int s = blockIdx.x * 256 + threadIdx.x;
    float acc = 0.f;
    #pragma unroll
    for (int j = 0; j < 2; j++) {
        int d = j * Ss + s;
        int p = pos[d];
        if (p < Cc) {
            int ee = esel[d];
            acc += gates[d] * (rowsum[ee * Cc + p] + b2sum[ee]);
        }
    }
    vals[s] = acc;
}

// ---------------- per-batch log-softmax over T (streaming, 8 KB per block) ----------------
__global__ __launch_bounds__(1024) void k_lsm(const float* __restrict__ vals,
                                              float* __restrict__ out) {
    int b = blockIdx.x; int t = threadIdx.x;
    __shared__ float red[1024];
    float v0 = vals[b * Tt + t];
    float v1 = vals[b * Tt + t + 1024];
    float m = fmaxf(v0, v1);
    red[t] = m; __syncthreads();
    for (int st = 512; st; st >>= 1) { if (t < st) red[t] = fmaxf(red[t], red[t + st]); __syncthreads(); }
    float mx = red[0];
    __syncthreads();
    float se = expf(v0 - mx) + expf(v1 - mx);
    red[t] = se; __syncthreads();
    for (int st = 512; st; st >>= 1) { if (t < st) red[t] += red[t + st]; __syncthreads(); }
    float lse = logf(red[0]);
    out[b * Tt + t] = v0 - mx - lse;
    out[b * Tt + t + 1024] = v1 - mx - lse;
}

extern "C" void kernel_launch(void* const* d_in, const int* in_sizes, int n_in,
                              void* d_out, int out_size, void* d_ws, size_t ws_size,
                              hipStream_t stream) {
    const float* x  = (const float*)d_in[0];
    const float* wg = (const float*)d_in[1];
    const float* w1 = (const float*)d_in[2];
    const float* b1 = (const float*)d_in[3];
    const float* w2 = (const float*)d_in[4];
    const float* b2 = (const float*)d_in[5];
    float* out = (float*)d_out;

    char* ws = (char*)d_ws;
    size_t off = 0;
    auto alloc = [&](size_t bytes) -> void* {
        void* p = ws + off;
        off += (bytes + 255) & ~(size_t)255;
        return p;
    };
    // rowsum + srcidx adjacent -> single memset
    float* rowsum   = (float*)alloc((size_t)Ee * Cc * 4 + (size_t)Ee * Cc * 4);
    int*   srcidx   = (int*)(rowsum + (size_t)Ee * Cc);
    float* w2sum    = (float*)alloc((size_t)Ee * Hh * 4);
    float* b2sum    = (float*)alloc(Ee * 4);
    int*   esel     = (int*)alloc((size_t)2 * Ss * 4);
    int*   lrank    = (int*)alloc((size_t)2 * Ss * 4);
    int*   blockhist= (int*)alloc((size_t)64 * 8 * 4);
    int*   blockbase= (int*)alloc((size_t)64 * 8 * 4);
    int*   pos      = (int*)alloc((size_t)2 * Ss * 4);
    float* gates    = (float*)alloc((size_t)2 * Ss * 4);
    __hip_bfloat16* xbf = (__hip_bfloat16*)alloc((size_t)Ss * Mm * 2);
    __hip_bfloat16* w1t = (__hip_bfloat16*)alloc((size_t)Ee * Hh * Mm * 2);

    hipMemsetAsync(rowsum, 0, (size_t)2 * Ee * Cc * 4, stream);
    k_prep<<<10241, 256, 0, stream>>>(w1, w2, b2, x, wg, w1t, w2sum, b2sum, esel, gates, xbf);
    k_posA<<<64, 256, 0, stream>>>(esel, lrank, blockhist);
    k_posB<<<1, 512, 0, stream>>>(blockhist, blockbase);
    k_sidx<<<64, 256, 0, stream>>>(esel, lrank, blockbase, pos, srcidx);
    k_gemm<<<2048, 256, 0, stream>>>(xbf, srcidx, w1t, b1, w2sum, rowsum);
    float* vals = (float*)lrank;   // lrank is dead after k_sidx; reuse as vals[S]
    k_combine<<<32, 256, 0, stream>>>(esel, pos, gates, rowsum, b2sum, vals);
    k_lsm<<<Bb, 1024, 0, stream>>>(vals, out);
}

// Round 5
// 307.124 us; speedup vs baseline: 1.0166x; 1.0166x over previous
//
#include <hip/hip_runtime.h>
#include <hip/hip_bf16.h>
#include <cstdint>
#include <cstddef>

// Problem constants
constexpr int Bb = 4;
constexpr int Tt = 2048;
constexpr int Mm = 1024;
constexpr int Hh = 2048;
constexpr int Ee = 8;
constexpr int Ss = Bb * Tt;   // 8192
constexpr int Cc = 2048;      // capacity per expert

typedef __attribute__((ext_vector_type(4))) float f32x4;
typedef __attribute__((ext_vector_type(8))) short bf16x8;

__device__ inline void load_lds16(const void* g, void* l) {
    __builtin_amdgcn_global_load_lds(
        (const __attribute__((address_space(1))) unsigned int*)g,
        (__attribute__((address_space(3))) unsigned int*)l, 16, 0, 0);
}

// ---------------- fused prep: w1 transpose+cast | w2sum/b2sum | gate + x->bf16 ----------------
// blocks [0,4096): w1 (E,M,H) fp32 -> w1t (E,H,M) bf16
// blocks [4096,8192): w2sum[e,h] = sum_m w2[e,h,m]   block 8192: b2sum
// blocks [8193,10241): gating (one wave per token) + xbf emit
__global__ __launch_bounds__(256) void k_prep(
    const float* __restrict__ w1, const float* __restrict__ w2, const float* __restrict__ b2,
    const float* __restrict__ x, const float* __restrict__ wg,
    __hip_bfloat16* __restrict__ w1t, float* __restrict__ w2sum, float* __restrict__ b2sum,
    int* __restrict__ esel, float* __restrict__ gates, __hip_bfloat16* __restrict__ xbf) {
    int bid = blockIdx.x;
    int t = threadIdx.x;
    if (bid < 4096) {
        // ---- w1 transpose: 64x64 tile; h-idx = bid&31, m-idx = (bid>>5)&15, e = bid>>9
        __shared__ float tile[64][65];
        int e = bid >> 9, m0 = ((bid >> 5) & 15) * 64, h0 = (bid & 31) * 64;
        const float* src = w1 + (size_t)e * Mm * Hh;
        #pragma unroll
        for (int i = 0; i < 4; i++) {
            int idx = t + i * 256;            // [0,1024)
            int r = idx >> 4, c4 = idx & 15;  // r: m-row, c4: h-chunk of 4
            float4 v = *(const float4*)(src + (size_t)(m0 + r) * Hh + h0 + c4 * 4);
            tile[r][c4 * 4 + 0] = v.x; tile[r][c4 * 4 + 1] = v.y;
            tile[r][c4 * 4 + 2] = v.z; tile[r][c4 * 4 + 3] = v.w;
        }
        __syncthreads();
        __hip_bfloat16* dst = w1t + (size_t)e * Hh * Mm;
        #pragma unroll
        for (int i = 0; i < 2; i++) {
            int idx = t + i * 256;            // [0,512)
            int r = idx >> 3, c8 = idx & 7;   // r: h-row, c8: m-chunk of 8
            __hip_bfloat16 tmp[8];
            #pragma unroll
            for (int k = 0; k < 8; k++) tmp[k] = __float2bfloat16(tile[c8 * 8 + k][r]);
            uint4 vv; __builtin_memcpy(&vv, tmp, 16);
            *(uint4*)(dst + (size_t)(h0 + r) * Mm + m0 + c8 * 8) = vv;
        }
    } else if (bid < 8192) {
        // ---- w2sum: 4 rows per block (one per wave)
        int wave = t >> 6, lane = t & 63;
        int r = (bid - 4096) * 4 + wave;   // r in [0, E*H)
        const float4* p = (const float4*)(w2 + (size_t)r * Mm);
        float s = 0.f;
        #pragma unroll
        for (int i = 0; i < 4; i++) { float4 v = p[lane + i * 64]; s += v.x + v.y + v.z + v.w; }
        #pragma unroll
        for (int off = 32; off; off >>= 1) s += __shfl_down(s, off);
        if (lane == 0) w2sum[r] = s;
    } else if (bid == 8192) {
        // ---- b2sum: 4 waves x 2 half-waves = 8 experts
        int wave = t >> 6, lane = t & 63;
        int e = wave * 2 + (lane >> 5);
        int l = lane & 31;
        const float4* p = (const float4*)(b2 + (size_t)e * Mm);
        float s = 0.f;
        #pragma unroll
        for (int i = 0; i < 8; i++) { float4 v = p[l + i * 32]; s += v.x + v.y + v.z + v.w; }
        #pragma unroll
        for (int off = 16; off; off >>= 1) s += __shfl_down(s, off);
        if (l == 0) b2sum[e] = s;
    } else {
        // ---- gating: one wave per token + bf16 emit
        int gb = bid - 8193;
        int s = (gb * 256 + t) >> 6;   // token id
        int lane = t & 63;
        const float4* xr = (const float4*)(x + (size_t)s * Mm);
        const float4* wgr = (const float4*)wg;
        float acc[8];
        #pragma unroll
        for (int e = 0; e < 8; e++) acc[e] = 0.f;
        #pragma unroll
        for (int i = 0; i < 4; i++) {
            float4 xv = xr[lane + i * 64];
            __hip_bfloat16 tb[4];
            tb[0] = __float2bfloat16(xv.x); tb[1] = __float2bfloat16(xv.y);
            tb[2] = __float2bfloat16(xv.z); tb[3] = __float2bfloat16(xv.w);
            uint2 u; __builtin_memcpy(&u, tb, 8);
            *(uint2*)(xbf + (size_t)s * Mm + (lane + i * 64) * 4) = u;
            int mbase = (lane + i * 64) * 4;
            #pragma unroll
            for (int k = 0; k < 4; k++) {
                int m = mbase + k;
                float xm = (k == 0) ? xv.x : (k == 1) ? xv.y : (k == 2) ? xv.z : xv.w;
                float4 w0 = wgr[m * 2], w1v = wgr[m * 2 + 1];
                acc[0] += xm * w0.x;  acc[1] += xm * w0.y;  acc[2] += xm * w0.z;  acc[3] += xm * w0.w;
                acc[4] += xm * w1v.x; acc[5] += xm * w1v.y; acc[6] += xm * w1v.z; acc[7] += xm * w1v.w;
            }
        }
        #pragma unroll
        for (int off = 32; off; off >>= 1)
            #pragma unroll
            for (int e = 0; e < 8; e++) acc[e] += __shfl_down(acc[e], off);
        if (lane == 0) {
            float mx = acc[0];
            #pragma unroll
            for (int e = 1; e < 8; e++) mx = fmaxf(mx, acc[e]);
            float p[8], se = 0.f;
            #pragma unroll
            for (int e = 0; e < 8; e++) { p[e] = expf(acc[e] - mx); se += p[e]; }
            float inv = 1.f / se;
            #pragma unroll
            for (int e = 0; e < 8; e++) p[e] *= inv;
            int i0 = 0; float v0 = p[0];
            #pragma unroll
            for (int e = 1; e < 8; e++) if (p[e] > v0) { v0 = p[e]; i0 = e; }
            int i1 = -1; float v1 = -1.f;
            #pragma unroll
            for (int e = 0; e < 8; e++) if (e != i0 && p[e] > v1) { v1 = p[e]; i1 = e; }
            float den = v0 + v1 + 1e-9f;
            esel[s] = i0; esel[Ss + s] = i1;
            gates[s] = v0 / den; gates[Ss + s] = v1 / den;
        }
    }
}

// ---------------- positions: parallel 2-phase scan (j-major = linear d) ----------------
__global__ __launch_bounds__(256) void k_posA(const int* __restrict__ esel,
                                              int* __restrict__ lrank, int* __restrict__ blockhist) {
    int b = blockIdx.x, t = threadIdx.x;
    int d = b * 256 + t;
    int e = esel[d];
    int wave = t >> 6, lane = t & 63;
    __shared__ int wh[4][8];
    unsigned long long mymask = 0;
    #pragma unroll
    for (int q = 0; q < 8; q++) {
        unsigned long long m = __ballot(e == q);
        if (q == e) mymask = m;
        if (lane == 0) wh[wave][q] = (int)__popcll(m);
    }
    __syncthreads();
    int prefix = (int)__popcll(mymask & ((1ull << lane) - 1ull));
    for (int w = 0; w < wave; w++) prefix += wh[w][e];
    lrank[d] = prefix;
    if (t < 8) blockhist[b * 8 + t] = wh[0][t] + wh[1][t] + wh[2][t] + wh[3][t];
}

// parallel exclusive scan over the 64 block-histograms: wave q handles expert q
__global__ __launch_bounds__(512) void k_posB(const int* __restrict__ blockhist,
                                              int* __restrict__ blockbase) {
    int t = threadIdx.x;
    int wave = t >> 6, lane = t & 63;   // wave = expert q, lane = block b
    int v = blockhist[lane * 8 + wave];
    int x = v;
    #pragma unroll
    for (int off = 1; off < 64; off <<= 1) {
        int y = __shfl_up(x, off);
        if (lane >= off) x += y;
    }
    blockbase[lane * 8 + wave] = x - v;   // exclusive prefix
}

// ---------------- finalize positions + build inverse index srcidx[e][c] = token ----------------
__global__ __launch_bounds__(256) void k_sidx(const int* __restrict__ esel,
                                              const int* __restrict__ lrank,
                                              const int* __restrict__ blockbase,
                                              int* __restrict__ pos, int* __restrict__ srcidx) {
    int d = blockIdx.x * 256 + threadIdx.x;
    int e = esel[d];
    int p = blockbase[(d >> 8) * 8 + e] + lrank[d];
    pos[d] = p;
    if (p < Cc) srcidx[e * Cc + p] = d & (Ss - 1);
}

// ---------------- fused expert GEMM (A gathered via srcidx) + relu + w2sum reduction ----------------
// Round-7 structure: 256x256 tile, 8 waves (2 c-halves x 4 h-quarters), BK=32,
// 4-buffer K-tile ring (stage j+3 while computing j, vmcnt(8) counted waits),
// ONE barrier per K-step, 32 MFMA per wave per barrier (2x round-4's amortization).
// LDS slot permutation (verified 0-conflict + coalesced in round 3/4):
//   slot s (16 B) holds row s>>2, k-chunk ((s&3) - ((s>>3)&3)) & 3.
//   fragment read (rowgroup G, r16, quad): slot G*64 + r16*4 + ((quad + (r16>>1)) & 3).
// Ring safety: tile j+3 staged into buf (j+3)&3 = buf (j-1)&3, issued AFTER the barrier
// of iteration j; all LDS reads of iteration j-1 completed (into registers) before that
// barrier, so the overwrite cannot race. vmcnt(8) at the top of iteration j waits for
// tile j's 4 staging loads (tiles j+1, j+2 stay in flight).
__global__ __launch_bounds__(512, 2) void k_gemm(
    const __hip_bfloat16* __restrict__ xbf, const int* __restrict__ srcidx,
    const __hip_bfloat16* __restrict__ w1t,
    const float* __restrict__ b1, const float* __restrict__ w2sum,
    float* __restrict__ rowsum) {
    // 4 ring buffers x (256 rows x 32 k) bf16 for each of A, B = 128 KiB total
    __shared__ __align__(16) __hip_bfloat16 As[4][256 * 32];
    __shared__ __align__(16) __hip_bfloat16 Bs[4][256 * 32];
    int bid = blockIdx.x;
    // XCD-affine: e = bid & 7 -> expert e pinned to XCD e; w1t[e] (4 MB) lives in that L2.
    int e = bid & 7;
    int tile = bid >> 3;              // [0,64)
    int cb = tile >> 3, hb = tile & 7;
    int c0 = cb * 256, h0 = hb * 256;
    int t = threadIdx.x;              // [0,512)
    int wave = t >> 6, lane = t & 63;
    int wm = wave >> 2;               // c-half   [0,2)
    int wn = wave & 3;                // h-quarter [0,4)
    int r16 = lane & 15, quad = lane >> 4;
    // staging decode: thread t fills slot t (rows 0-127) and slot 512+t (rows 128-255)
    int r_s = t >> 2;                              // [0,128)
    int qd = ((t & 3) - ((t >> 3) & 3)) & 3;       // within-row k-chunk permutation
    int s0 = srcidx[e * Cc + c0 + r_s];
    int s1 = srcidx[e * Cc + c0 + 128 + r_s];
    const __hip_bfloat16* a0 = xbf + (size_t)s0 * Mm + qd * 8;
    const __hip_bfloat16* a1 = xbf + (size_t)s1 * Mm + qd * 8;
    const __hip_bfloat16* Bp = w1t + (size_t)e * Hh * Mm;
    const __hip_bfloat16* b0 = Bp + (size_t)(h0 + r_s) * Mm + qd * 8;
    const __hip_bfloat16* b1p = Bp + (size_t)(h0 + 128 + r_s) * Mm + qd * 8;
    // fragment-read slot offset within each 64-slot row-group
    int fo = r16 * 4 + ((quad + (r16 >> 1)) & 3);
    f32x4 acc[8][4];
    #pragma unroll
    for (int i = 0; i < 8; i++)
        #pragma unroll
        for (int j = 0; j < 4; j++) acc[i][j] = (f32x4){0.f, 0.f, 0.f, 0.f};

    // prologue: stage K-tiles 0,1,2 into bufs 0,1,2 (12 loads in flight)
    #pragma unroll
    for (int p = 0; p < 3; p++) {
        int k0 = p * 32;
        load_lds16(a0 + k0,  As[p] + t * 8);
        load_lds16(a1 + k0,  As[p] + (512 + t) * 8);
        load_lds16(b0 + k0,  Bs[p] + t * 8);
        load_lds16(b1p + k0, Bs[p] + (512 + t) * 8);
    }

    // main loop: iterations 0..28 stage tile j+3; tiles 29-31 handled in the tail
    for (int j = 0; j < 29; ++j) {
        __builtin_amdgcn_sched_barrier(0);
        asm volatile("s_waitcnt vmcnt(8)" ::: "memory");   // tile j landed; j+1, j+2 in flight
        __builtin_amdgcn_s_barrier();
        __builtin_amdgcn_sched_barrier(0);
        {   // stage tile j+3 into buf (j+3)&3 (= buf consumed in iteration j-1)
            int b = (j + 3) & 3;
            int k0 = (j + 3) * 32;
            load_lds16(a0 + k0,  As[b] + t * 8);
            load_lds16(a1 + k0,  As[b] + (512 + t) * 8);
            load_lds16(b0 + k0,  Bs[b] + t * 8);
            load_lds16(b1p + k0, Bs[b] + (512 + t) * 8);
        }
        const __hip_bfloat16* Ar = As[j & 3];
        const __hip_bfloat16* Br = Bs[j & 3];
        bf16x8 bfr[4];
        #pragma unroll
        for (int ni = 0; ni < 4; ni++)
            bfr[ni] = *(const bf16x8*)(Br + ((wn * 4 + ni) * 64 + fo) * 8);
        __builtin_amdgcn_s_setprio(1);
        #pragma unroll
        for (int mi = 0; mi < 8; mi++) {
            bf16x8 af = *(const bf16x8*)(Ar + ((wm * 8 + mi) * 64 + fo) * 8);
            #pragma unroll
            for (int ni = 0; ni < 4; ni++)
                acc[mi][ni] = __builtin_amdgcn_mfma_f32_16x16x32_bf16(af, bfr[ni], acc[mi][ni], 0, 0, 0);
        }
        __builtin_amdgcn_s_setprio(0);
    }
    // tail: tiles 29, 30, 31 (no more staging)
    #pragma unroll
    for (int j = 29; j < 32; ++j) {
        __builtin_amdgcn_sched_barrier(0);
        if (j == 29)      asm volatile("s_waitcnt vmcnt(8)" ::: "memory");
        else if (j == 30) asm volatile("s_waitcnt vmcnt(4)" ::: "memory");
        else              asm volatile("s_waitcnt vmcnt(0)" ::: "memory");
        __builtin_amdgcn_s_barrier();
        __builtin_amdgcn_sched_barrier(0);
        const __hip_bfloat16* Ar = As[j & 3];
        const __hip_bfloat16* Br = Bs[j & 3];
        bf16x8 bfr[4];
        #pragma unroll
        for (int ni = 0; ni < 4; ni++)
            bfr[ni] = *(const bf16x8*)(Br + ((wn * 4 + ni) * 64 + fo) * 8);
        __builtin_amdgcn_s_setprio(1);
        #pragma unroll
        for (int mi = 0; mi < 8; mi++) {
            bf16x8 af = *(const bf16x8*)(Ar + ((wm * 8 + mi) * 64 + fo) * 8);
            #pragma unroll
            for (int ni = 0; ni < 4; ni++)
                acc[mi][ni] = __builtin_amdgcn_mfma_f32_16x16x32_bf16(af, bfr[ni], acc[mi][ni], 0, 0, 0);
        }
        __builtin_amdgcn_s_setprio(0);
    }
    __builtin_amdgcn_sched_barrier(0);

    // epilogue: relu(s + b1) * w2sum, reduce over h, atomic into rowsum[e, c]
    float b1v[4], wsv[4];
    #pragma unroll
    for (int ni = 0; ni < 4; ni++) {
        int hg = h0 + wn * 64 + ni * 16 + r16;
        b1v[ni] = b1[e * Hh + hg];
        wsv[ni] = w2sum[e * Hh + hg];
    }
    #pragma unroll
    for (int mi = 0; mi < 8; mi++) {
        #pragma unroll
        for (int r = 0; r < 4; r++) {
            float val = 0.f;
            #pragma unroll
            for (int ni = 0; ni < 4; ni++) {
                float sv = acc[mi][ni][r] + b1v[ni];
                val += fmaxf(sv, 0.f) * wsv[ni];
            }
            #pragma unroll
            for (int off = 1; off < 16; off <<= 1) val += __shfl_xor(val, off);
            if (r16 == 0) {
                int cg = c0 + wm * 128 + mi * 16 + quad * 4 + r;
                atomicAdd(&rowsum[e * Cc + cg], val);
            }
        }
    }
}

// ---------------- combine (parallel gather) ----------------
__global__ __launch_bounds__(256) void k_combine(
    const int* __restrict__ esel, const int* __restrict__ pos,
    const float* __restrict__ gates, const float* __restrict__ rowsum,
    const float* __restrict__ b2sum, float* __restrict__ vals) {
    int s = blockIdx.x * 256 + threadIdx.x;
    float acc = 0.f;
    #pragma unroll
    for (int j = 0; j < 2; j++) {
        int d = j * Ss + s;
        int p = pos[d];
        if (p < Cc) {
            int ee = esel[d];
            acc += gates[d] * (rowsum[ee * Cc + p] + b2sum[ee]);
        }
    }
    vals[s] = acc;
}

// ---------------- per-batch log-softmax over T (streaming, 8 KB per block) ----------------
__global__ __launch_bounds__(1024) void k_lsm(const float* __restrict__ vals,
                                              float* __restrict__ out) {
    int b = blockIdx.x; int t = threadIdx.x;
    __shared__ float red[1024];
    float v0 = vals[b * Tt + t];
    float v1 = vals[b * Tt + t + 1024];
    float m = fmaxf(v0, v1);
    red[t] = m; __syncthreads();
    for (int st = 512; st; st >>= 1) { if (t < st) red[t] = fmaxf(red[t], red[t + st]); __syncthreads(); }
    float mx = red[0];
    __syncthreads();
    float se = expf(v0 - mx) + expf(v1 - mx);
    red[t] = se; __syncthreads();
    for (int st = 512; st; st >>= 1) { if (t < st) red[t] += red[t + st]; __syncthreads(); }
    float lse = logf(red[0]);
    out[b * Tt + t] = v0 - mx - lse;
    out[b * Tt + t + 1024] = v1 - mx - lse;
}

extern "C" void kernel_launch(void* const* d_in, const int* in_sizes, int n_in,
                              void* d_out, int out_size, void* d_ws, size_t ws_size,
                              hipStream_t stream) {
    const float* x  = (const float*)d_in[0];
    const float* wg = (const float*)d_in[1];
    const float* w1 = (const float*)d_in[2];
    const float* b1 = (const float*)d_in[3];
    const float* w2 = (const float*)d_in[4];
    const float* b2 = (const float*)d_in[5];
    float* out = (float*)d_out;

    char* ws = (char*)d_ws;
    size_t off = 0;
    auto alloc = [&](size_t bytes) -> void* {
        void* p = ws + off;
        off += (bytes + 255) & ~(size_t)255;
        return p;
    };
    // rowsum + srcidx adjacent -> single memset
    float* rowsum   = (float*)alloc((size_t)Ee * Cc * 4 + (size_t)Ee * Cc * 4);
    int*   srcidx   = (int*)(rowsum + (size_t)Ee * Cc);
    float* w2sum    = (float*)alloc((size_t)Ee * Hh * 4);
    float* b2sum    = (float*)alloc(Ee * 4);
    int*   esel     = (int*)alloc((size_t)2 * Ss * 4);
    int*   lrank    = (int*)alloc((size_t)2 * Ss * 4);
    int*   blockhist= (int*)alloc((size_t)64 * 8 * 4);
    int*   blockbase= (int*)alloc((size_t)64 * 8 * 4);
    int*   pos      = (int*)alloc((size_t)2 * Ss * 4);
    float* gates    = (float*)alloc((size_t)2 * Ss * 4);
    __hip_bfloat16* xbf = (__hip_bfloat16*)alloc((size_t)Ss * Mm * 2);
    __hip_bfloat16* w1t = (__hip_bfloat16*)alloc((size_t)Ee * Hh * Mm * 2);

    hipMemsetAsync(rowsum, 0, (size_t)2 * Ee * Cc * 4, stream);
    k_prep<<<10241, 256, 0, stream>>>(w1, w2, b2, x, wg, w1t, w2sum, b2sum, esel, gates, xbf);
    k_posA<<<64, 256, 0, stream>>>(esel, lrank, blockhist);
    k_posB<<<1, 512, 0, stream>>>(blockhist, blockbase);
    k_sidx<<<64, 256, 0, stream>>>(esel, lrank, blockbase, pos, srcidx);
    k_gemm<<<512, 512, 0, stream>>>(xbf, srcidx, w1t, b1, w2sum, rowsum);
    float* vals = (float*)lrank;   // lrank is dead after k_sidx; reuse as vals[S]
    k_combine<<<32, 256, 0, stream>>>(esel, pos, gates, rowsum, b2sum, vals);
    k_lsm<<<Bb, 1024, 0, stream>>>(vals, out);
}

// Round 7
// 287.875 us; speedup vs baseline: 1.0846x; 1.0669x over previous
//
#include <hip/hip_runtime.h>
#include <hip/hip_bf16.h>
#include <cstdint>
#include <cstddef>

// Problem constants
constexpr int Bb = 4;
constexpr int Tt = 2048;
constexpr int Mm = 1024;
constexpr int Hh = 2048;
constexpr int Ee = 8;
constexpr int Ss = Bb * Tt;   // 8192
constexpr int Cc = 2048;      // capacity per expert

typedef __attribute__((ext_vector_type(4))) float f32x4;
typedef __attribute__((ext_vector_type(8))) short bf16x8;

__device__ inline void load_lds16(const void* g, void* l) {
    __builtin_amdgcn_global_load_lds(
        (const __attribute__((address_space(1))) unsigned int*)g,
        (__attribute__((address_space(3))) unsigned int*)l, 16, 0, 0);
}

// ---------------- fused prep: w1 transpose+cast | w2sum/b2sum | gate + x->bf16 ----------------
__global__ __launch_bounds__(256) void k_prep(
    const float* __restrict__ w1, const float* __restrict__ w2, const float* __restrict__ b2,
    const float* __restrict__ x, const float* __restrict__ wg,
    __hip_bfloat16* __restrict__ w1t, float* __restrict__ w2sum, float* __restrict__ b2sum,
    int* __restrict__ esel, float* __restrict__ gates, __hip_bfloat16* __restrict__ xbf) {
    int bid = blockIdx.x;
    int t = threadIdx.x;
    if (bid < 4096) {
        __shared__ float tile[64][65];
        int e = bid >> 9, m0 = ((bid >> 5) & 15) * 64, h0 = (bid & 31) * 64;
        const float* src = w1 + (size_t)e * Mm * Hh;
        #pragma unroll
        for (int i = 0; i < 4; i++) {
            int idx = t + i * 256;
            int r = idx >> 4, c4 = idx & 15;
            float4 v = *(const float4*)(src + (size_t)(m0 + r) * Hh + h0 + c4 * 4);
            tile[r][c4 * 4 + 0] = v.x; tile[r][c4 * 4 + 1] = v.y;
            tile[r][c4 * 4 + 2] = v.z; tile[r][c4 * 4 + 3] = v.w;
        }
        __syncthreads();
        __hip_bfloat16* dst = w1t + (size_t)e * Hh * Mm;
        #pragma unroll
        for (int i = 0; i < 2; i++) {
            int idx = t + i * 256;
            int r = idx >> 3, c8 = idx & 7;
            __hip_bfloat16 tmp[8];
            #pragma unroll
            for (int k = 0; k < 8; k++) tmp[k] = __float2bfloat16(tile[c8 * 8 + k][r]);
            uint4 vv; __builtin_memcpy(&vv, tmp, 16);
            *(uint4*)(dst + (size_t)(h0 + r) * Mm + m0 + c8 * 8) = vv;
        }
    } else if (bid < 8192) {
        int wave = t >> 6, lane = t & 63;
        int r = (bid - 4096) * 4 + wave;
        const float4* p = (const float4*)(w2 + (size_t)r * Mm);
        float s = 0.f;
        #pragma unroll
        for (int i = 0; i < 4; i++) { float4 v = p[lane + i * 64]; s += v.x + v.y + v.z + v.w; }
        #pragma unroll
        for (int off = 32; off; off >>= 1) s += __shfl_down(s, off);
        if (lane == 0) w2sum[r] = s;
    } else if (bid == 8192) {
        int wave = t >> 6, lane = t & 63;
        int e = wave * 2 + (lane >> 5);
        int l = lane & 31;
        const float4* p = (const float4*)(b2 + (size_t)e * Mm);
        float s = 0.f;
        #pragma unroll
        for (int i = 0; i < 8; i++) { float4 v = p[l + i * 32]; s += v.x + v.y + v.z + v.w; }
        #pragma unroll
        for (int off = 16; off; off >>= 1) s += __shfl_down(s, off);
        if (l == 0) b2sum[e] = s;
    } else {
        int gb = bid - 8193;
        int s = (gb * 256 + t) >> 6;
        int lane = t & 63;
        const float4* xr = (const float4*)(x + (size_t)s * Mm);
        const float4* wgr = (const float4*)wg;
        float acc[8];
        #pragma unroll
        for (int e = 0; e < 8; e++) acc[e] = 0.f;
        #pragma unroll
        for (int i = 0; i < 4; i++) {
            float4 xv = xr[lane + i * 64];
            __hip_bfloat16 tb[4];
            tb[0] = __float2bfloat16(xv.x); tb[1] = __float2bfloat16(xv.y);
            tb[2] = __float2bfloat16(xv.z); tb[3] = __float2bfloat16(xv.w);
            uint2 u; __builtin_memcpy(&u, tb, 8);
            *(uint2*)(xbf + (size_t)s * Mm + (lane + i * 64) * 4) = u;
            int mbase = (lane + i * 64) * 4;
            #pragma unroll
            for (int k = 0; k < 4; k++) {
                int m = mbase + k;
                float xm = (k == 0) ? xv.x : (k == 1) ? xv.y : (k == 2) ? xv.z : xv.w;
                float4 w0 = wgr[m * 2], w1v = wgr[m * 2 + 1];
                acc[0] += xm * w0.x;  acc[1] += xm * w0.y;  acc[2] += xm * w0.z;  acc[3] += xm * w0.w;
                acc[4] += xm * w1v.x; acc[5] += xm * w1v.y; acc[6] += xm * w1v.z; acc[7] += xm * w1v.w;
            }
        }
        #pragma unroll
        for (int off = 32; off; off >>= 1)
            #pragma unroll
            for (int e = 0; e < 8; e++) acc[e] += __shfl_down(acc[e], off);
        if (lane == 0) {
            float mx = acc[0];
            #pragma unroll
            for (int e = 1; e < 8; e++) mx = fmaxf(mx, acc[e]);
            float p[8], se = 0.f;
            #pragma unroll
            for (int e = 0; e < 8; e++) { p[e] = expf(acc[e] - mx); se += p[e]; }
            float inv = 1.f / se;
            #pragma unroll
            for (int e = 0; e < 8; e++) p[e] *= inv;
            int i0 = 0; float v0 = p[0];
            #pragma unroll
            for (int e = 1; e < 8; e++) if (p[e] > v0) { v0 = p[e]; i0 = e; }
            int i1 = -1; float v1 = -1.f;
            #pragma unroll
            for (int e = 0; e < 8; e++) if (e != i0 && p[e] > v1) { v1 = p[e]; i1 = e; }
            float den = v0 + v1 + 1e-9f;
            esel[s] = i0; esel[Ss + s] = i1;
            gates[s] = v0 / den; gates[Ss + s] = v1 / den;
        }
    }
}

// ---------------- positions: parallel 2-phase scan ----------------
__global__ __launch_bounds__(256) void k_posA(const int* __restrict__ esel,
                                              int* __restrict__ lrank, int* __restrict__ blockhist) {
    int b = blockIdx.x, t = threadIdx.x;
    int d = b * 256 + t;
    int e = esel[d];
    int wave = t >> 6, lane = t & 63;
    __shared__ int wh[4][8];
    unsigned long long mymask = 0;
    #pragma unroll
    for (int q = 0; q < 8; q++) {
        unsigned long long m = __ballot(e == q);
        if (q == e) mymask = m;
        if (lane == 0) wh[wave][q] = (int)__popcll(m);
    }
    __syncthreads();
    int prefix = (int)__popcll(mymask & ((1ull << lane) - 1ull));
    for (int w = 0; w < wave; w++) prefix += wh[w][e];
    lrank[d] = prefix;
    if (t < 8) blockhist[b * 8 + t] = wh[0][t] + wh[1][t] + wh[2][t] + wh[3][t];
}

__global__ __launch_bounds__(512) void k_posB(const int* __restrict__ blockhist,
                                              int* __restrict__ blockbase) {
    int t = threadIdx.x;
    int wave = t >> 6, lane = t & 63;
    int v = blockhist[lane * 8 + wave];
    int x = v;
    #pragma unroll
    for (int off = 1; off < 64; off <<= 1) {
        int y = __shfl_up(x, off);
        if (lane >= off) x += y;
    }
    blockbase[lane * 8 + wave] = x - v;
}

__global__ __launch_bounds__(256) void k_sidx(const int* __restrict__ esel,
                                              const int* __restrict__ lrank,
                                              const int* __restrict__ blockbase,
                                              int* __restrict__ pos, int* __restrict__ srcidx) {
    int d = blockIdx.x * 256 + threadIdx.x;
    int e = esel[d];
    int p = blockbase[(d >> 8) * 8 + e] + lrank[d];
    pos[d] = p;
    if (p < Cc) srcidx[e * Cc + p] = d & (Ss - 1);
}

// ---------------- fused expert GEMM: 256x256 tile, 8-phase schedule (T3+T4) ----------------
// (unchanged resubmit of round-6; round-6 bench was an infra failure, not a kernel result)
// Per phase: 8 ds_read_b128 (one (mh,kk) quadrant's frags) || stage 1 half (2 gload_lds)
//   -> barrier -> lgkmcnt(0)+sched_barrier -> setprio(1) 16 MFMA setprio(0)
//   -> [vmcnt(8) at even phases] -> barrier.
// Stage schedule (iter i; tiles 2i,2i+1 computed):
//   P1: A[1][1](2i+1)  P2: B[1][1](2i+1)  P3: A[0][0](2i+2)  P4: B[0][0](2i+2)
//   P5: A[0][1](2i+2)  P6: B[0][1](2i+2)  P7: A[1][0](2i+3)  P8: B[1][0](2i+3)
// vmcnt(8) at end of P2/P4/P6/P8 retires exactly the two stages (4 gloads) needed by the
// NEXT phase's ds_reads (12 gloads outstanding steady-state). Tail peels 8/4/0.
// Slot permutation within each 16KB quarter = the round-3/5 verified layout
// (0 bank conflicts + coalesced staging): slot s holds row s>>2, chunk ((s&3)-((s>>3)&3))&3;
// fragment read offset fo = r16*4 + ((quad + (r16>>1)) & 3).
__global__ __launch_bounds__(512, 2) void k_gemm(
    const __hip_bfloat16* __restrict__ xbf, const int* __restrict__ srcidx,
    const __hip_bfloat16* __restrict__ w1t,
    const float* __restrict__ b1, const float* __restrict__ w2sum,
    float* __restrict__ rowsum) {
    __shared__ __align__(16) __hip_bfloat16 A_lds[2][2][8192];   // [db][khalf][256r x 32k]
    __shared__ __align__(16) __hip_bfloat16 B_lds[2][2][8192];
    int bid = blockIdx.x;
    int e = bid & 7;                  // XCD-affine: expert e -> XCD e
    int tile = bid >> 3;              // [0,64)
    int cb = tile >> 3, hb = tile & 7;
    int c0 = cb * 256, h0 = hb * 256;
    int t = threadIdx.x;              // [0,512)
    int wave = t >> 6, lane = t & 63;
    int wm = wave >> 2;               // c-half   [0,2)
    int wn = wave & 3;                // h-quarter [0,4)
    int r16 = lane & 15, quad = lane >> 4;
    // staging decode (verified r3/r5): thread t fills slot t (rows 0-127) and 512+t (rows 128-255)
    int r_s = t >> 2;
    int qd = ((t & 3) - ((t >> 3) & 3)) & 3;
    int s0 = srcidx[e * Cc + c0 + r_s];
    int s1 = srcidx[e * Cc + c0 + 128 + r_s];
    const __hip_bfloat16* a0 = xbf + (size_t)s0 * Mm + qd * 8;
    const __hip_bfloat16* a1 = xbf + (size_t)s1 * Mm + qd * 8;
    const __hip_bfloat16* Bp = w1t + (size_t)e * Hh * Mm;
    const __hip_bfloat16* b0 = Bp + (size_t)(h0 + r_s) * Mm + qd * 8;
    const __hip_bfloat16* b1p = Bp + (size_t)(h0 + 128 + r_s) * Mm + qd * 8;
    int fo = r16 * 4 + ((quad + (r16 >> 1)) & 3);
    int lsl = t * 8, hsl = (512 + t) * 8;
    f32x4 acc[8][4];
    #pragma unroll
    for (int i = 0; i < 8; i++)
        #pragma unroll
        for (int j = 0; j < 4; j++) acc[i][j] = (f32x4){0.f, 0.f, 0.f, 0.f};

#define STAGE_A(DB, KK, T) do { \
    load_lds16(a0 + (T) * 64 + (KK) * 32, &A_lds[DB][KK][lsl]); \
    load_lds16(a1 + (T) * 64 + (KK) * 32, &A_lds[DB][KK][hsl]); } while (0);
#define STAGE_B(DB, KK, T) do { \
    load_lds16(b0 + (T) * 64 + (KK) * 32, &B_lds[DB][KK][lsl]); \
    load_lds16(b1p + (T) * 64 + (KK) * 32, &B_lds[DB][KK][hsl]); } while (0);
#define NOSTAGE
#define VM8 asm volatile("s_waitcnt vmcnt(8)" ::: "memory");
#define VM4 asm volatile("s_waitcnt vmcnt(4)" ::: "memory");
#define VM0 asm volatile("s_waitcnt vmcnt(0)" ::: "memory");
#define VMNONE

#define PHASE(DB, KK, MH, STAGE_STMT, VM_STMT) do { \
    __builtin_amdgcn_sched_barrier(0); \
    bf16x8 paf[4], pbf[4]; \
    const __hip_bfloat16* Ab_ = &A_lds[DB][KK][0]; \
    const __hip_bfloat16* Bb_ = &B_lds[DB][KK][0]; \
    _Pragma("unroll") \
    for (int q_ = 0; q_ < 4; q_++) { \
        paf[q_] = *(const bf16x8*)(Ab_ + ((wm * 8 + (MH) * 4 + q_) * 64 + fo) * 8); \
        pbf[q_] = *(const bf16x8*)(Bb_ + ((wn * 4 + q_) * 64 + fo) * 8); \
    } \
    STAGE_STMT \
    __builtin_amdgcn_s_barrier(); \
    asm volatile("s_waitcnt lgkmcnt(0)" ::: "memory"); \
    __builtin_amdgcn_sched_barrier(0); \
    __builtin_amdgcn_s_setprio(1); \
    _Pragma("unroll") \
    for (int mi_ = 0; mi_ < 4; mi_++) \
        _Pragma("unroll") \
        for (int ni_ = 0; ni_ < 4; ni_++) \
            acc[(MH) * 4 + mi_][ni_] = __builtin_amdgcn_mfma_f32_16x16x32_bf16( \
                paf[mi_], pbf[ni_], acc[(MH) * 4 + mi_][ni_], 0, 0, 0); \
    __builtin_amdgcn_s_setprio(0); \
    __builtin_amdgcn_sched_barrier(0); \
    VM_STMT \
    __builtin_amdgcn_s_barrier(); \
} while (0)

    // prologue: quarters needed through iter-0 P6 (order matters for vmcnt accounting)
    STAGE_A(0, 0, 0) STAGE_B(0, 0, 0) STAGE_A(0, 1, 0) STAGE_B(0, 1, 0)
    STAGE_A(1, 0, 1) STAGE_B(1, 0, 1)
    asm volatile("s_waitcnt vmcnt(8)" ::: "memory");   // tile-0 k-half-0 (A,B) landed
    __builtin_amdgcn_s_barrier();

    for (int i = 0; i < 7; ++i) {
        int T1 = 2 * i + 1, T2 = 2 * i + 2, T3 = 2 * i + 3;
        PHASE(0, 0, 0, STAGE_A(1, 1, T1), VMNONE);
        PHASE(0, 0, 1, STAGE_B(1, 1, T1), VM8);
        PHASE(0, 1, 0, STAGE_A(0, 0, T2), VMNONE);
        PHASE(0, 1, 1, STAGE_B(0, 0, T2), VM8);
        PHASE(1, 0, 0, STAGE_A(0, 1, T2), VMNONE);
        PHASE(1, 0, 1, STAGE_B(0, 1, T2), VM8);
        PHASE(1, 1, 0, STAGE_A(1, 0, T3), VMNONE);
        PHASE(1, 1, 1, STAGE_B(1, 0, T3), VM8);
    }
    // peeled last iteration (tiles 14, 15): no further staging past P2
    PHASE(0, 0, 0, STAGE_A(1, 1, 15), VMNONE);
    PHASE(0, 0, 1, STAGE_B(1, 1, 15), VM8);
    PHASE(0, 1, 0, NOSTAGE, VMNONE);
    PHASE(0, 1, 1, NOSTAGE, VM4);
    PHASE(1, 0, 0, NOSTAGE, VMNONE);
    PHASE(1, 0, 1, NOSTAGE, VM0);
    PHASE(1, 1, 0, NOSTAGE, VMNONE);
    PHASE(1, 1, 1, NOSTAGE, VMNONE);

    // epilogue: relu(s + b1) * w2sum, reduce over h, atomic into rowsum[e, c]
    float b1v[4], wsv[4];
    #pragma unroll
    for (int ni = 0; ni < 4; ni++) {
        int hg = h0 + wn * 64 + ni * 16 + r16;
        b1v[ni] = b1[e * Hh + hg];
        wsv[ni] = w2sum[e * Hh + hg];
    }
    #pragma unroll
    for (int mi = 0; mi < 8; mi++) {
        #pragma unroll
        for (int r = 0; r < 4; r++) {
            float val = 0.f;
            #pragma unroll
            for (int ni = 0; ni < 4; ni++) {
                float sv = acc[mi][ni][r] + b1v[ni];
                val += fmaxf(sv, 0.f) * wsv[ni];
            }
            #pragma unroll
            for (int off = 1; off < 16; off <<= 1) val += __shfl_xor(val, off);
            if (r16 == 0) {
                int cg = c0 + wm * 128 + mi * 16 + quad * 4 + r;
                atomicAdd(&rowsum[e * Cc + cg], val);
            }
        }
    }
}

// ---------------- combine (parallel gather) ----------------
__global__ __launch_bounds__(256) void k_combine(
    const int* __restrict__ esel, const int* __restrict__ pos,
    const float* __restrict__ gates, const float* __restrict__ rowsum,
    const float* __restrict__ b2sum, float* __restrict__ vals) {
    int s = blockIdx.x * 256 + threadIdx.x;
    float acc = 0.f;
    #pragma unroll
    for (int j = 0; j < 2; j++) {
        int d = j * Ss + s;
        int p = pos[d];
        if (p < Cc) {
            int ee = esel[d];
            acc += gates[d] * (rowsum[ee * Cc + p] + b2sum[ee]);
        }
    }
    vals[s] = acc;
}

// ---------------- per-batch log-softmax over T ----------------
__global__ __launch_bounds__(1024) void k_lsm(const float* __restrict__ vals,
                                              float* __restrict__ out) {
    int b = blockIdx.x; int t = threadIdx.x;
    __shared__ float red[1024];
    float v0 = vals[b * Tt + t];
    float v1 = vals[b * Tt + t + 1024];
    float m = fmaxf(v0, v1);
    red[t] = m; __syncthreads();
    for (int st = 512; st; st >>= 1) { if (t < st) red[t] = fmaxf(red[t], red[t + st]); __syncthreads(); }
    float mx = red[0];
    __syncthreads();
    float se = expf(v0 - mx) + expf(v1 - mx);
    red[t] = se; __syncthreads();
    for (int st = 512; st; st >>= 1) { if (t < st) red[t] += red[t + st]; __syncthreads(); }
    float lse = logf(red[0]);
    out[b * Tt + t] = v0 - mx - lse;
    out[b * Tt + t + 1024] = v1 - mx - lse;
}

extern "C" void kernel_launch(void* const* d_in, const int* in_sizes, int n_in,
                              void* d_out, int out_size, void* d_ws, size_t ws_size,
                              hipStream_t stream) {
    const float* x  = (const float*)d_in[0];
    const float* wg = (const float*)d_in[1];
    const float* w1 = (const float*)d_in[2];
    const float* b1 = (const float*)d_in[3];
    const float* w2 = (const float*)d_in[4];
    const float* b2 = (const float*)d_in[5];
    float* out = (float*)d_out;

    char* ws = (char*)d_ws;
    size_t off = 0;
    auto alloc = [&](size_t bytes) -> void* {
        void* p = ws + off;
        off += (bytes + 255) & ~(size_t)255;
        return p;
    };
    float* rowsum   = (float*)alloc((size_t)Ee * Cc * 4 + (size_t)Ee * Cc * 4);
    int*   srcidx   = (int*)(rowsum + (size_t)Ee * Cc);
    float* w2sum    = (float*)alloc((size_t)Ee * Hh * 4);
    float* b2sum    = (float*)alloc(Ee * 4);
    int*   esel     = (int*)alloc((size_t)2 * Ss * 4);
    int*   lrank    = (int*)alloc((size_t)2 * Ss * 4);
    int*   blockhist= (int*)alloc((size_t)64 * 8 * 4);
    int*   blockbase= (int*)alloc((size_t)64 * 8 * 4);
    int*   pos      = (int*)alloc((size_t)2 * Ss * 4);
    float* gates    = (float*)alloc((size_t)2 * Ss * 4);
    __hip_bfloat16* xbf = (__hip_bfloat16*)alloc((size_t)Ss * Mm * 2);
    __hip_bfloat16* w1t = (__hip_bfloat16*)alloc((size_t)Ee * Hh * Mm * 2);

    hipMemsetAsync(rowsum, 0, (size_t)2 * Ee * Cc * 4, stream);
    k_prep<<<10241, 256, 0, stream>>>(w1, w2, b2, x, wg, w1t, w2sum, b2sum, esel, gates, xbf);
    k_posA<<<64, 256, 0, stream>>>(esel, lrank, blockhist);
    k_posB<<<1, 512, 0, stream>>>(blockhist, blockbase);
    k_sidx<<<64, 256, 0, stream>>>(esel, lrank, blockbase, pos, srcidx);
    k_gemm<<<512, 512, 0, stream>>>(xbf, srcidx, w1t, b1, w2sum, rowsum);
    float* vals = (float*)lrank;
    k_combine<<<32, 256, 0, stream>>>(esel, pos, gates, rowsum, b2sum, vals);
    k_lsm<<<Bb, 1024, 0, stream>>>(vals, out);
}